// Round 3
// baseline (694.967 us; speedup 1.0000x reference)
//
#include <hip/hip_runtime.h>
#include <hip/hip_bf16.h>

#define BATCH 4
#define CH 256
#define CRD 32
#define NN 4096

typedef __bf16 bf16x8 __attribute__((ext_vector_type(8)));
typedef float floatx4 __attribute__((ext_vector_type(4)));
typedef float floatx16 __attribute__((ext_vector_type(16)));
typedef unsigned short ushort4v __attribute__((ext_vector_type(4)));
typedef unsigned short ushort8v __attribute__((ext_vector_type(8)));

static __device__ __forceinline__ unsigned short f2bf(float f) {
    unsigned int u = __float_as_uint(f);
    u += 0x7fff + ((u >> 16) & 1);           // RNE
    return (unsigned short)(u >> 16);
}
static __device__ __forceinline__ float bf2f(unsigned short h) {
    return __uint_as_float((unsigned int)h << 16);
}

// ---------------------------------------------------------------------------
// K0: weight prep. Wt[c][320] f32 (q rows pre-scaled by 1/sqrt(32)),
// Wob[o][c] bf16. grid 320 blocks x 256 threads.
// ---------------------------------------------------------------------------
__global__ __launch_bounds__(256) void wconv_kernel(
    const float* __restrict__ Wq, const float* __restrict__ Wk,
    const float* __restrict__ Wv, const float* __restrict__ Wo,
    float* __restrict__ Wt, unsigned short* __restrict__ Wob)
{
    const int o = blockIdx.x;
    const int t = threadIdx.x;
    float scale = 1.0f;
    const float* src;
    if (o < 32)      { src = Wq + o * 256; scale = 0.17677669529663687f; }
    else if (o < 64) { src = Wk + (o - 32) * 256; }
    else             { src = Wv + (o - 64) * 256; }
    Wt[t * 320 + o] = src[t] * scale;
    if (o < 256) Wob[o * 256 + t] = f2bf(Wo[o * 256 + t]);
}

// ---------------------------------------------------------------------------
// K1: QKV conv, scalar-uniform W loads (no LDS). q,k: bf16 [B][N][32];
// v: bf16 [B][C][N]. grid (16 ntile, 10 otile, 4 b), block 256.
// ---------------------------------------------------------------------------
__global__ __launch_bounds__(256) void qkv_kernel(
    const float* __restrict__ x, const float* __restrict__ Wt,
    unsigned short* __restrict__ q, unsigned short* __restrict__ k,
    unsigned short* __restrict__ v_t)
{
    const int t = threadIdx.x;
    const int n = blockIdx.x * 256 + t;
    const int oy = blockIdx.y;
    const int ob = oy * 32;
    const int b = blockIdx.z;
    const float* xb = x + (size_t)b * CH * NN;

    float acc[32];
    #pragma unroll
    for (int o = 0; o < 32; ++o) acc[o] = 0.f;

    float xv = xb[n];
    for (int c = 0; c < 256; ++c) {
        float xn = (c < 255) ? xb[(size_t)(c + 1) * NN + n] : 0.f;
        const float* wr = Wt + c * 320 + ob;   // wave-uniform -> s_load
        #pragma unroll
        for (int o = 0; o < 32; ++o) acc[o] = fmaf(wr[o], xv, acc[o]);
        xv = xn;
    }

    if (oy <= 1) {
        unsigned short* dst = (oy == 0 ? q : k) + ((size_t)(b * NN + n)) * 32;
        #pragma unroll
        for (int g = 0; g < 4; ++g) {
            ushort8v p;
            #pragma unroll
            for (int i = 0; i < 8; ++i) p[i] = f2bf(acc[g * 8 + i]);
            *(ushort8v*)(dst + g * 8) = p;
        }
    } else {
        const int cb = ob - 64;
        #pragma unroll
        for (int o = 0; o < 32; ++o)
            v_t[((size_t)(b * CH + cb + o)) * NN + n] = f2bf(acc[o]);
    }
}

// ---------------------------------------------------------------------------
// K2: register-fragment flash attention.
// grid (64 q-groups, 2 key-splits, 4 b), block 256 (4 waves).
// Wave roles: qh = w>>1 (query half for scores), kh = w&1 (key half),
// and channel quarter c0=64w for PV. Scores/PV: mfma_f32_32x32x16_bf16.
// Writes unnormalized O-partials bf16 [bid][c][q] + (m,l) to ws.
// ---------------------------------------------------------------------------
__global__ __launch_bounds__(256, 2) void attn_kernel(
    const unsigned short* __restrict__ qg, const unsigned short* __restrict__ kg,
    const unsigned short* __restrict__ vt, unsigned short* __restrict__ Opart,
    float* __restrict__ ml)
{
    __shared__ unsigned short p_lds[4096];      // frag-major P, 8 KB
    __shared__ float m_state[2][64];
    __shared__ float pmax_s[2][64];
    __shared__ float psum_s[2][64];
    __shared__ float alpha_s[64];

    const int t = threadIdx.x;
    const int w = t >> 6;
    const int l = t & 63;
    const int l31 = l & 31;
    const int h = l >> 5;
    const int qh = w >> 1, kh = w & 1;
    const int g = blockIdx.x, ks = blockIdx.y, b = blockIdx.z;
    const int qbase = g * 64;
    const int kstart = ks * 2048;
    const int q_idx = qh * 32 + l31;

    const unsigned short* qb = qg + (size_t)b * NN * CRD;
    const unsigned short* kb = kg + (size_t)b * NN * CRD;
    const unsigned short* vb = vt + (size_t)b * CH * NN;

    // Q B-frags (resident): B[k=c][n=query]
    bf16x8 qf[2];
    #pragma unroll
    for (int ch = 0; ch < 2; ++ch)
        qf[ch] = *(const bf16x8*)(qb + (size_t)(qbase + qh * 32 + l31) * 32 + ch * 16 + h * 8);

    if (t < 64) m_state[0][t] = -1e30f;

    floatx16 acc[2][2];
    #pragma unroll
    for (int a = 0; a < 2; ++a)
        #pragma unroll
        for (int c = 0; c < 2; ++c)
            #pragma unroll
            for (int i = 0; i < 16; ++i) acc[a][c][i] = 0.f;
    float l_run = 0.f;

    // prologue: prefetch K/V frags for iter 0
    bf16x8 kf[2][2], vf[2][8];
    #pragma unroll
    for (int ch = 0; ch < 2; ++ch)
        kf[0][ch] = *(const bf16x8*)(kb + (size_t)(kstart + kh * 32 + l31) * 32 + ch * 16 + h * 8);
    #pragma unroll
    for (int ct = 0; ct < 2; ++ct)
        #pragma unroll
        for (int kc = 0; kc < 4; ++kc)
            vf[0][ct * 4 + kc] = *(const bf16x8*)(vb + (size_t)(64 * w + 32 * ct + l31) * NN
                                                  + kstart + kc * 16 + h * 8);
    __syncthreads();

    for (int it = 0; it < 32; ++it) {
        const int cur = it & 1, nxt = cur ^ 1;

        // ---- phase 1: scores S[key 32][query 32] for this wave's quadrant ----
        floatx16 sacc;
        #pragma unroll
        for (int i = 0; i < 16; ++i) sacc[i] = 0.f;
        sacc = __builtin_amdgcn_mfma_f32_32x32x16_bf16(kf[cur][0], qf[0], sacc, 0, 0, 0);
        sacc = __builtin_amdgcn_mfma_f32_32x32x16_bf16(kf[cur][1], qf[1], sacc, 0, 0, 0);

        float pm = sacc[0];
        #pragma unroll
        for (int r = 1; r < 16; ++r) pm = fmaxf(pm, sacc[r]);
        pm = fmaxf(pm, __shfl_xor(pm, 32));
        pmax_s[kh][q_idx] = pm;
        __syncthreads();   // A

        // ---- phase 2: online softmax for this wave's quadrant ----
        float mold = m_state[cur][q_idx];
        float mnew = fmaxf(mold, fmaxf(pmax_s[0][q_idx], pmax_s[1][q_idx]));
        float alpha = __expf(mold - mnew);
        float pv[16];
        float psum = 0.f;
        #pragma unroll
        for (int r = 0; r < 16; ++r) {
            pv[r] = __expf(sacc[r] - mnew);
            psum += pv[r];
        }
        psum += __shfl_xor(psum, 32);
        psum_s[kh][q_idx] = psum;
        #pragma unroll
        for (int gr = 0; gr < 4; ++gr) {
            ushort4v pk;
            #pragma unroll
            for (int i = 0; i < 4; ++i) pk[i] = f2bf(pv[gr * 4 + i]);
            int kc = 2 * kh + (gr >> 1);
            int lane2 = l31 + 32 * (gr & 1);
            int idx = ((kc * 2 + qh) * 64 + lane2) * 8 + 4 * h;
            *(ushort4v*)&p_lds[idx] = pk;
        }
        if (kh == 0) {
            m_state[nxt][q_idx] = mnew;
            alpha_s[q_idx] = alpha;
        }
        __syncthreads();   // B

        // ---- phase 3: prefetch next K/V, rescale, PV ----
        if (it + 1 < 32) {
            const int kb2 = kstart + (it + 1) * 64;
            #pragma unroll
            for (int ch = 0; ch < 2; ++ch)
                kf[nxt][ch] = *(const bf16x8*)(kb + (size_t)(kb2 + kh * 32 + l31) * 32 + ch * 16 + h * 8);
            #pragma unroll
            for (int ct = 0; ct < 2; ++ct)
                #pragma unroll
                for (int kc = 0; kc < 4; ++kc)
                    vf[nxt][ct * 4 + kc] = *(const bf16x8*)(vb + (size_t)(64 * w + 32 * ct + l31) * NN
                                                            + kb2 + kc * 16 + h * 8);
        }

        float a0 = alpha_s[l31];
        float a1 = alpha_s[32 + l31];
        #pragma unroll
        for (int ct = 0; ct < 2; ++ct)
            #pragma unroll
            for (int i = 0; i < 16; ++i) {
                acc[ct][0][i] *= a0;
                acc[ct][1][i] *= a1;
            }
        #pragma unroll
        for (int kc = 0; kc < 4; ++kc) {
            bf16x8 p0 = *(const bf16x8*)&p_lds[((kc * 2 + 0) * 64 + l) * 8];
            bf16x8 p1 = *(const bf16x8*)&p_lds[((kc * 2 + 1) * 64 + l) * 8];
            acc[0][0] = __builtin_amdgcn_mfma_f32_32x32x16_bf16(vf[cur][kc], p0, acc[0][0], 0, 0, 0);
            acc[1][0] = __builtin_amdgcn_mfma_f32_32x32x16_bf16(vf[cur][4 + kc], p0, acc[1][0], 0, 0, 0);
            acc[0][1] = __builtin_amdgcn_mfma_f32_32x32x16_bf16(vf[cur][kc], p1, acc[0][1], 0, 0, 0);
            acc[1][1] = __builtin_amdgcn_mfma_f32_32x32x16_bf16(vf[cur][4 + kc], p1, acc[1][1], 0, 0, 0);
        }
        if (kh == 0)
            l_run = l_run * alpha + psum_s[0][q_idx] + psum_s[1][q_idx];
    }

    // ---- epilogue: store unnormalized O bf16 [bid][c][q] + (m,l) ----
    const size_t bid = (size_t)(b * 2 + ks) * 64 + g;
    unsigned short* op = Opart + bid * (CH * 64);
    #pragma unroll
    for (int ct = 0; ct < 2; ++ct)
        #pragma unroll
        for (int qp = 0; qp < 2; ++qp)
            #pragma unroll
            for (int r = 0; r < 16; ++r) {
                int c = 64 * w + 32 * ct + (r & 3) + 8 * (r >> 2) + 4 * h;
                op[c * 64 + qp * 32 + l31] = f2bf(acc[ct][qp][r]);
            }
    if (kh == 0 && h == 0) {
        ml[bid * 128 + q_idx] = m_state[0][q_idx];
        ml[bid * 128 + 64 + q_idx] = l_run;
    }
}

// ---------------------------------------------------------------------------
// K3: combine key-split partials + Wo GEMM (MFMA) + gamma*out + x.
// grid (64 n-tiles, 4 b), block 256 (4 waves, wave w -> o in [64w,64w+64)).
// ---------------------------------------------------------------------------
__global__ __launch_bounds__(256, 2) void out_kernel(
    const unsigned short* __restrict__ Opart, const float* __restrict__ ml,
    const unsigned short* __restrict__ Wob, const float* __restrict__ x,
    const float* __restrict__ gamma, float* __restrict__ out)
{
    __shared__ unsigned short frag[32768 / 2];   // 16 ch x 2 nt x 64 lanes x 8 us = 32 KB
    __shared__ float wgt[2][64];

    const int t = threadIdx.x;
    const int w = t >> 6;
    const int l = t & 63;
    const int l31 = l & 31;
    const int h = l >> 5;
    const int g = blockIdx.x, b = blockIdx.y;

    const size_t bid0 = (size_t)(b * 2 + 0) * 64 + g;
    const size_t bid1 = (size_t)(b * 2 + 1) * 64 + g;

    if (t < 64) {
        float m0 = ml[bid0 * 128 + t], l0 = ml[bid0 * 128 + 64 + t];
        float m1 = ml[bid1 * 128 + t], l1 = ml[bid1 * 128 + 64 + t];
        float M = fmaxf(m0, m1);
        float e0 = __expf(m0 - M), e1 = __expf(m1 - M);
        float L = l0 * e0 + l1 * e1;
        wgt[0][t] = e0 / L;
        wgt[1][t] = e1 / L;
    }
    __syncthreads();

    // combine partials -> frag-major bf16 attn tile [256 c][64 n]
    {
        const unsigned short* o0 = Opart + bid0 * (CH * 64);
        const unsigned short* o1 = Opart + bid1 * (CH * 64);
        const int n = t & 63;
        const int cg = t >> 6;
        const float w0 = wgt[0][n], w1 = wgt[1][n];
        const int nt = n >> 5, n31 = n & 31;
        for (int ci = 0; ci < 64; ++ci) {
            int c = cg * 64 + ci;
            float v = w0 * bf2f(o0[c * 64 + n]) + w1 * bf2f(o1[c * 64 + n]);
            int ch = c >> 4, hb = (c >> 3) & 1, j = c & 7;
            frag[((ch * 2 + nt) * 64 + n31 + 32 * hb) * 8 + j] = f2bf(v);
        }
    }
    __syncthreads();

    floatx16 acc[2][2];
    #pragma unroll
    for (int a = 0; a < 2; ++a)
        #pragma unroll
        for (int c = 0; c < 2; ++c)
            #pragma unroll
            for (int i = 0; i < 16; ++i) acc[a][c][i] = 0.f;

    for (int ch = 0; ch < 16; ++ch) {
        bf16x8 bf0 = *(const bf16x8*)&frag[((ch * 2 + 0) * 64 + l) * 8];
        bf16x8 bf1 = *(const bf16x8*)&frag[((ch * 2 + 1) * 64 + l) * 8];
        #pragma unroll
        for (int ot = 0; ot < 2; ++ot) {
            bf16x8 af = *(const bf16x8*)(Wob + (size_t)(64 * w + ot * 32 + l31) * 256 + ch * 16 + h * 8);
            acc[ot][0] = __builtin_amdgcn_mfma_f32_32x32x16_bf16(af, bf0, acc[ot][0], 0, 0, 0);
            acc[ot][1] = __builtin_amdgcn_mfma_f32_32x32x16_bf16(af, bf1, acc[ot][1], 0, 0, 0);
        }
    }

    const float gm = gamma[0];
    #pragma unroll
    for (int ot = 0; ot < 2; ++ot)
        #pragma unroll
        for (int nt = 0; nt < 2; ++nt)
            #pragma unroll
            for (int r = 0; r < 16; ++r) {
                int o = 64 * w + ot * 32 + (r & 3) + 8 * (r >> 2) + 4 * h;
                int n = g * 64 + nt * 32 + l31;
                size_t oi = ((size_t)(b * 256 + o)) * NN + n;
                out[oi] = gm * acc[ot][nt][r] + x[oi];
            }
}

// ---------------------------------------------------------------------------
extern "C" void kernel_launch(void* const* d_in, const int* in_sizes, int n_in,
                              void* d_out, int out_size, void* d_ws, size_t ws_size,
                              hipStream_t stream)
{
    const float* x     = (const float*)d_in[0];
    const float* Wq    = (const float*)d_in[1];
    const float* Wk    = (const float*)d_in[2];
    const float* Wv    = (const float*)d_in[3];
    const float* Wo    = (const float*)d_in[4];
    const float* gamma = (const float*)d_in[5];
    float* out = (float*)d_out;

    char* wsb = (char*)d_ws;
    unsigned short* q     = (unsigned short*)(wsb);                     // 1 MB
    unsigned short* k     = (unsigned short*)(wsb + (1u << 20));        // 1 MB
    unsigned short* vt    = (unsigned short*)(wsb + (2u << 20));        // 8 MB
    float*          Wt    = (float*)         (wsb + (10u << 20));       // 320 KB
    unsigned short* Wob   = (unsigned short*)(wsb + (10u << 20) + (512u << 10)); // 128 KB
    unsigned short* Opart = (unsigned short*)(wsb + (11u << 20));       // 16 MB
    float*          ml    = (float*)         (wsb + (27u << 20));       // 256 KB

    wconv_kernel<<<320, 256, 0, stream>>>(Wq, Wk, Wv, Wo, Wt, Wob);

    dim3 g1(16, 10, BATCH);
    qkv_kernel<<<g1, 256, 0, stream>>>(x, Wt, q, k, vt);

    dim3 g2(64, 2, BATCH);
    attn_kernel<<<g2, 256, 0, stream>>>(q, k, vt, Opart, ml);

    dim3 g3(64, BATCH);
    out_kernel<<<g3, 256, 0, stream>>>(Opart, ml, Wob, x, gamma, out);
}

// Round 4
// 438.188 us; speedup vs baseline: 1.5860x; 1.5860x over previous
//
#include <hip/hip_runtime.h>
#include <hip/hip_bf16.h>

#define BATCH 4
#define CH 256
#define CRD 32
#define NN 4096

typedef __bf16 bf16x8 __attribute__((ext_vector_type(8)));
typedef float floatx4 __attribute__((ext_vector_type(4)));
typedef float floatx16 __attribute__((ext_vector_type(16)));
typedef unsigned short ushort4v __attribute__((ext_vector_type(4)));
typedef unsigned short ushort8v __attribute__((ext_vector_type(8)));

static __device__ __forceinline__ unsigned short f2bf(float f) {
    unsigned int u = __float_as_uint(f);
    u += 0x7fff + ((u >> 16) & 1);           // RNE
    return (unsigned short)(u >> 16);
}
static __device__ __forceinline__ float bf2f(unsigned short h) {
    return __uint_as_float((unsigned int)h << 16);
}

// ---------------------------------------------------------------------------
// K0: weight prep. Wt[c][320] f32 (q rows pre-scaled), Wob[o][c] bf16.
// ---------------------------------------------------------------------------
__global__ __launch_bounds__(256) void wconv_kernel(
    const float* __restrict__ Wq, const float* __restrict__ Wk,
    const float* __restrict__ Wv, const float* __restrict__ Wo,
    float* __restrict__ Wt, unsigned short* __restrict__ Wob)
{
    const int o = blockIdx.x;
    const int t = threadIdx.x;
    float scale = 1.0f;
    const float* src;
    if (o < 32)      { src = Wq + o * 256; scale = 0.17677669529663687f; }
    else if (o < 64) { src = Wk + (o - 32) * 256; }
    else             { src = Wv + (o - 64) * 256; }
    Wt[t * 320 + o] = src[t] * scale;
    if (o < 256) Wob[o * 256 + t] = f2bf(Wo[o * 256 + t]);
}

// ---------------------------------------------------------------------------
// K1: QKV conv, 64 outputs/block, scalar-uniform W loads.
// q,k: bf16 [B][N][32]; v: bf16 [B][C][N]. grid (16, 5, 4), block 256.
// ---------------------------------------------------------------------------
__global__ __launch_bounds__(256) void qkv_kernel(
    const float* __restrict__ x, const float* __restrict__ Wt,
    unsigned short* __restrict__ q, unsigned short* __restrict__ k,
    unsigned short* __restrict__ v_t)
{
    const int t = threadIdx.x;
    const int n = blockIdx.x * 256 + t;
    const int oy = blockIdx.y;
    const int ob = oy * 64;
    const int b = blockIdx.z;
    const float* xb = x + (size_t)b * CH * NN;

    float acc[64];
    #pragma unroll
    for (int o = 0; o < 64; ++o) acc[o] = 0.f;

    float xv = xb[n];
    for (int c = 0; c < 256; ++c) {
        float xn = (c < 255) ? xb[(size_t)(c + 1) * NN + n] : 0.f;
        const float* wr = Wt + c * 320 + ob;   // wave-uniform -> s_load
        #pragma unroll
        for (int o = 0; o < 64; ++o) acc[o] = fmaf(wr[o], xv, acc[o]);
        xv = xn;
    }

    if (oy == 0) {
        unsigned short* qd = q + ((size_t)(b * NN + n)) * 32;
        unsigned short* kd = k + ((size_t)(b * NN + n)) * 32;
        #pragma unroll
        for (int g = 0; g < 4; ++g) {
            ushort8v pq, pk;
            #pragma unroll
            for (int i = 0; i < 8; ++i) {
                pq[i] = f2bf(acc[g * 8 + i]);
                pk[i] = f2bf(acc[32 + g * 8 + i]);
            }
            *(ushort8v*)(qd + g * 8) = pq;
            *(ushort8v*)(kd + g * 8) = pk;
        }
    } else {
        const int cb = (oy - 1) * 64;
        #pragma unroll
        for (int o = 0; o < 64; ++o)
            v_t[((size_t)(b * CH + cb + o)) * NN + n] = f2bf(acc[o]);
    }
}

// ---------------------------------------------------------------------------
// K2: register-budgeted flash attention. QT=32 queries/block, MT=128 keys/iter,
// no key-split. grid (128, 4), block 256 (4 waves), launch_bounds (256,4).
// Wave w: score slice keys [32w,32w+32); PV channels [64w,64w+64).
// 2 barriers/iter. Writes normalized bf16 O [B][C][N].
// ---------------------------------------------------------------------------
__global__ __launch_bounds__(256, 4) void attn_kernel(
    const unsigned short* __restrict__ qg, const unsigned short* __restrict__ kg,
    const unsigned short* __restrict__ vt, unsigned short* __restrict__ attn)
{
    __shared__ unsigned short p_lds[8 * 64 * 8];   // 8 frags x 64 lanes x 8 bf16 = 8 KB
    __shared__ float pmax_s[4][32];
    __shared__ float psum_s[4][32];

    const int t = threadIdx.x;
    const int w = t >> 6;
    const int l = t & 63;
    const int l31 = l & 31;
    const int h = l >> 5;
    const int g = blockIdx.x, b = blockIdx.y;
    const int qbase = g * 32;
    const int c0 = 64 * w;

    const unsigned short* qb = qg + (size_t)b * NN * CRD;
    const unsigned short* kb = kg + (size_t)b * NN * CRD;
    const unsigned short* vg = vt + (size_t)b * CH * NN;

    // resident Q B-frags: col=q(l31), k=c
    bf16x8 qf0 = *(const bf16x8*)(qb + (size_t)(qbase + l31) * 32 + h * 8);
    bf16x8 qf1 = *(const bf16x8*)(qb + (size_t)(qbase + l31) * 32 + 16 + h * 8);

    float m_run = -1e30f;
    float l_run = 0.f;
    floatx16 acc0, acc1;
    #pragma unroll
    for (int i = 0; i < 16; ++i) { acc0[i] = 0.f; acc1[i] = 0.f; }

    for (int it = 0; it < 32; ++it) {
        const int k0 = it * 128;

        // ---- phase 1: scores S[32k][32q] for this wave's key slice ----
        bf16x8 kf0 = *(const bf16x8*)(kb + (size_t)(k0 + 32 * w + l31) * 32 + h * 8);
        bf16x8 kf1 = *(const bf16x8*)(kb + (size_t)(k0 + 32 * w + l31) * 32 + 16 + h * 8);
        floatx16 sacc;
        #pragma unroll
        for (int i = 0; i < 16; ++i) sacc[i] = 0.f;
        sacc = __builtin_amdgcn_mfma_f32_32x32x16_bf16(kf0, qf0, sacc, 0, 0, 0);
        sacc = __builtin_amdgcn_mfma_f32_32x32x16_bf16(kf1, qf1, sacc, 0, 0, 0);

        float pm = sacc[0];
        #pragma unroll
        for (int r = 1; r < 16; ++r) pm = fmaxf(pm, sacc[r]);
        pm = fmaxf(pm, __shfl_xor(pm, 32));
        if (h == 0) pmax_s[w][l31] = pm;
        __syncthreads();   // A

        // ---- phase 2: softmax, P -> LDS frag-major ----
        float mnew = fmaxf(fmaxf(pmax_s[0][l31], pmax_s[1][l31]),
                           fmaxf(pmax_s[2][l31], pmax_s[3][l31]));
        mnew = fmaxf(m_run, mnew);
        float alpha = __expf(m_run - mnew);
        m_run = mnew;
        float pv[16];
        float psum = 0.f;
        #pragma unroll
        for (int r = 0; r < 16; ++r) {
            pv[r] = __expf(sacc[r] - mnew);
            psum += pv[r];
        }
        psum += __shfl_xor(psum, 32);
        if (h == 0) psum_s[w][l31] = psum;
        #pragma unroll
        for (int rg = 0; rg < 4; ++rg) {
            ushort4v pk;
            #pragma unroll
            for (int i = 0; i < 4; ++i) pk[i] = f2bf(pv[rg * 4 + i]);
            // key offset 32w+8rg+4h+i -> frag 2w+(rg>>1), lane 32(rg&1)+l31, elem 4h+i
            int idx = (((2 * w + (rg >> 1)) * 64) + 32 * (rg & 1) + l31) * 8 + 4 * h;
            *(ushort4v*)&p_lds[idx] = pk;
        }
        __syncthreads();   // B

        // ---- phase 3: rescale + PV (depth-2 pipelined) ----
        float isum = (psum_s[0][l31] + psum_s[1][l31]) +
                     (psum_s[2][l31] + psum_s[3][l31]);
        l_run = l_run * alpha + isum;
        #pragma unroll
        for (int i = 0; i < 16; ++i) { acc0[i] *= alpha; acc1[i] *= alpha; }

        bf16x8 pf = *(const bf16x8*)&p_lds[l * 8];
        bf16x8 va = *(const bf16x8*)(vg + (size_t)(c0 + l31) * NN + k0 + h * 8);
        bf16x8 vb2 = *(const bf16x8*)(vg + (size_t)(c0 + 32 + l31) * NN + k0 + h * 8);
        #pragma unroll
        for (int kc = 0; kc < 8; ++kc) {
            bf16x8 pf_n, va_n, vb_n;
            if (kc < 7) {
                pf_n = *(const bf16x8*)&p_lds[((kc + 1) * 64 + l) * 8];
                va_n = *(const bf16x8*)(vg + (size_t)(c0 + l31) * NN + k0 + (kc + 1) * 16 + h * 8);
                vb_n = *(const bf16x8*)(vg + (size_t)(c0 + 32 + l31) * NN + k0 + (kc + 1) * 16 + h * 8);
            }
            acc0 = __builtin_amdgcn_mfma_f32_32x32x16_bf16(va, pf, acc0, 0, 0, 0);
            acc1 = __builtin_amdgcn_mfma_f32_32x32x16_bf16(vb2, pf, acc1, 0, 0, 0);
            pf = pf_n; va = va_n; vb2 = vb_n;
        }
    }

    // ---- epilogue: normalize, write bf16 [B][C][N] ----
    float inv = 1.f / l_run;
    unsigned short* ab = attn + (size_t)b * CH * NN;
    #pragma unroll
    for (int r = 0; r < 16; ++r) {
        int row = (r & 3) + 8 * (r >> 2) + 4 * h;
        ab[(size_t)(c0 + row) * NN + qbase + l31] = f2bf(acc0[r] * inv);
        ab[(size_t)(c0 + 32 + row) * NN + qbase + l31] = f2bf(acc1[r] * inv);
    }
}

// ---------------------------------------------------------------------------
// K3: Wo GEMM (MFMA) + gamma*out + x.  attn bf16 [B][C][N].
// grid (64 n-tiles, 4 b), block 256 (4 waves, wave w -> o in [64w,64w+64)).
// ---------------------------------------------------------------------------
__global__ __launch_bounds__(256, 2) void out_kernel(
    const unsigned short* __restrict__ attn, const unsigned short* __restrict__ Wob,
    const float* __restrict__ x, const float* __restrict__ gamma,
    float* __restrict__ out)
{
    __shared__ unsigned short frag[16 * 2 * 64 * 8];   // 32 KB

    const int t = threadIdx.x;
    const int w = t >> 6;
    const int l = t & 63;
    const int l31 = l & 31;
    const int h = l >> 5;
    const int g = blockIdx.x, b = blockIdx.y;

    // load attn tile [256c][64n] -> frag-major LDS
    {
        const unsigned short* ab = attn + (size_t)b * CH * NN + g * 64;
        const int n = t & 63;
        const int cg = t >> 6;
        const int nt = n >> 5, n31 = n & 31;
        for (int ci = 0; ci < 64; ++ci) {
            int c = cg * 64 + ci;
            unsigned short v = ab[(size_t)c * NN + n];
            int ch = c >> 4, hb = (c >> 3) & 1, j = c & 7;
            frag[((ch * 2 + nt) * 64 + n31 + 32 * hb) * 8 + j] = v;
        }
    }
    __syncthreads();

    floatx16 acc[2][2];
    #pragma unroll
    for (int a = 0; a < 2; ++a)
        #pragma unroll
        for (int c = 0; c < 2; ++c)
            #pragma unroll
            for (int i = 0; i < 16; ++i) acc[a][c][i] = 0.f;

    for (int ch = 0; ch < 16; ++ch) {
        bf16x8 bf0 = *(const bf16x8*)&frag[((ch * 2 + 0) * 64 + l) * 8];
        bf16x8 bf1 = *(const bf16x8*)&frag[((ch * 2 + 1) * 64 + l) * 8];
        #pragma unroll
        for (int ot = 0; ot < 2; ++ot) {
            bf16x8 af = *(const bf16x8*)(Wob + (size_t)(64 * w + ot * 32 + l31) * 256 + ch * 16 + h * 8);
            acc[ot][0] = __builtin_amdgcn_mfma_f32_32x32x16_bf16(af, bf0, acc[ot][0], 0, 0, 0);
            acc[ot][1] = __builtin_amdgcn_mfma_f32_32x32x16_bf16(af, bf1, acc[ot][1], 0, 0, 0);
        }
    }

    const float gm = gamma[0];
    #pragma unroll
    for (int ot = 0; ot < 2; ++ot)
        #pragma unroll
        for (int nt = 0; nt < 2; ++nt)
            #pragma unroll
            for (int r = 0; r < 16; ++r) {
                int o = 64 * w + ot * 32 + (r & 3) + 8 * (r >> 2) + 4 * h;
                int n = g * 64 + nt * 32 + l31;
                size_t oi = ((size_t)(b * 256 + o)) * NN + n;
                out[oi] = gm * acc[ot][nt][r] + x[oi];
            }
}

// ---------------------------------------------------------------------------
extern "C" void kernel_launch(void* const* d_in, const int* in_sizes, int n_in,
                              void* d_out, int out_size, void* d_ws, size_t ws_size,
                              hipStream_t stream)
{
    const float* x     = (const float*)d_in[0];
    const float* Wq    = (const float*)d_in[1];
    const float* Wk    = (const float*)d_in[2];
    const float* Wv    = (const float*)d_in[3];
    const float* Wo    = (const float*)d_in[4];
    const float* gamma = (const float*)d_in[5];
    float* out = (float*)d_out;

    char* wsb = (char*)d_ws;
    unsigned short* q    = (unsigned short*)(wsb);                       // 1 MB
    unsigned short* k    = (unsigned short*)(wsb + (1u << 20));          // 1 MB
    unsigned short* vt   = (unsigned short*)(wsb + (2u << 20));          // 8 MB
    float*          Wt   = (float*)         (wsb + (10u << 20));         // 320 KB
    unsigned short* Wob  = (unsigned short*)(wsb + (10u << 20) + (512u << 10)); // 128 KB
    unsigned short* attn = (unsigned short*)(wsb + (11u << 20));         // 8 MB

    wconv_kernel<<<320, 256, 0, stream>>>(Wq, Wk, Wv, Wo, Wt, Wob);

    dim3 g1(16, 5, BATCH);
    qkv_kernel<<<g1, 256, 0, stream>>>(x, Wt, q, k, vt);

    dim3 g2(128, BATCH);
    attn_kernel<<<g2, 256, 0, stream>>>(q, k, vt, attn);

    dim3 g3(64, BATCH);
    out_kernel<<<g3, 256, 0, stream>>>(attn, Wob, x, gamma, out);
}

// Round 5
// 246.480 us; speedup vs baseline: 2.8196x; 1.7778x over previous
//
#include <hip/hip_runtime.h>
#include <hip/hip_bf16.h>

#define BATCH 4
#define CH 256
#define CRD 32
#define NN 4096

typedef __bf16 bf16x8 __attribute__((ext_vector_type(8)));
typedef float floatx4 __attribute__((ext_vector_type(4)));
typedef float floatx16 __attribute__((ext_vector_type(16)));
typedef unsigned short ushort4v __attribute__((ext_vector_type(4)));
typedef unsigned short ushort8v __attribute__((ext_vector_type(8)));

static __device__ __forceinline__ unsigned short f2bf(float f) {
    unsigned int u = __float_as_uint(f);
    u += 0x7fff + ((u >> 16) & 1);           // RNE
    return (unsigned short)(u >> 16);
}

// ---------------------------------------------------------------------------
// K0: weight prep.
//  Wt2[oy][c][o&31] f32 (oy = o>>5; q rows pre-scaled by 1/sqrt(32))
//  WobF: Wo bf16 in MFMA A-frag-major order [mt][s][lane][8]
// grid 320 x 256.
// ---------------------------------------------------------------------------
__global__ __launch_bounds__(256) void wconv_kernel(
    const float* __restrict__ Wq, const float* __restrict__ Wk,
    const float* __restrict__ Wv, const float* __restrict__ Wo,
    float* __restrict__ Wt2, unsigned short* __restrict__ WobF)
{
    const int o = blockIdx.x;
    const int t = threadIdx.x;   // = input channel c
    float scale = 1.0f;
    const float* src;
    if (o < 32)      { src = Wq + o * 256; scale = 0.17677669529663687f; }
    else if (o < 64) { src = Wk + (o - 32) * 256; }
    else             { src = Wv + (o - 64) * 256; }
    Wt2[(o >> 5) * 8192 + t * 32 + (o & 31)] = src[t] * scale;
    if (o < 256) {
        int mt = o >> 5, s = t >> 4;
        int lane = (o & 31) + 32 * ((t >> 3) & 1);
        int j = t & 7;
        WobF[((mt * 16 + s) * 64 + lane) * 8 + j] = f2bf(Wo[o * 256 + t]);
    }
}

// ---------------------------------------------------------------------------
// K1: QKV conv, 32 outputs/block, SGPR-double-buffered W rows, 2-deep x
// prefetch. grid (16 ntile, 10 oy, 4 b) = 640 blocks, block 256.
// q,k: bf16 [B][N][32]; v: bf16 [B][C][N].
// ---------------------------------------------------------------------------
__global__ __launch_bounds__(256) void qkv_kernel(
    const float* __restrict__ x, const float* __restrict__ Wt2,
    unsigned short* __restrict__ q, unsigned short* __restrict__ k,
    unsigned short* __restrict__ v_t)
{
    const int t = threadIdx.x;
    const int n = blockIdx.x * 256 + t;
    const int oy = blockIdx.y;
    const int b = blockIdx.z;
    const float* xb = x + (size_t)b * CH * NN;
    const float* wrow = Wt2 + oy * 8192;

    float acc[32];
    #pragma unroll
    for (int o = 0; o < 32; ++o) acc[o] = 0.f;

    float wa[32], wb[32];
    #pragma unroll
    for (int o = 0; o < 32; ++o) wa[o] = wrow[o];

    float x0 = xb[n];
    float x1 = xb[NN + n];

    for (int c = 0; c < 256; c += 2) {
        const float* wn = wrow + (c + 1) * 32;
        #pragma unroll
        for (int o = 0; o < 32; ++o) wb[o] = wn[o];
        const int c2 = (c + 2 < 256) ? c + 2 : 255;
        const int c3 = (c + 3 < 256) ? c + 3 : 255;
        float x2 = xb[(size_t)c2 * NN + n];
        float x3 = xb[(size_t)c3 * NN + n];
        #pragma unroll
        for (int o = 0; o < 32; ++o) acc[o] = fmaf(wa[o], x0, acc[o]);
        const float* wn2 = wrow + c2 * 32;
        #pragma unroll
        for (int o = 0; o < 32; ++o) wa[o] = wn2[o];
        #pragma unroll
        for (int o = 0; o < 32; ++o) acc[o] = fmaf(wb[o], x1, acc[o]);
        x0 = x2; x1 = x3;
    }

    if (oy <= 1) {
        unsigned short* dst = (oy == 0 ? q : k) + ((size_t)(b * NN + n)) * 32;
        #pragma unroll
        for (int g2 = 0; g2 < 4; ++g2) {
            ushort8v p;
            #pragma unroll
            for (int i = 0; i < 8; ++i) p[i] = f2bf(acc[g2 * 8 + i]);
            *(ushort8v*)(dst + g2 * 8) = p;
        }
    } else {
        const int cb = (oy - 2) * 32;
        #pragma unroll
        for (int o = 0; o < 32; ++o)
            v_t[((size_t)(b * CH + cb + o)) * NN + n] = f2bf(acc[o]);
    }
}

// ---------------------------------------------------------------------------
// K2: flash attention with LDS-staged, XOR-swizzled V tiles.
// grid (128 q-tiles of 32, 4 b), block 256 (4 waves), 3 barriers/iter.
// Wave w: score key-slice [32w,+32); PV channels [64w,+64).
// Output: normalized bf16 O in K3-B-frag-major order.
// ---------------------------------------------------------------------------
__global__ __launch_bounds__(256, 2) void attn_kernel(
    const unsigned short* __restrict__ qg, const unsigned short* __restrict__ kg,
    const unsigned short* __restrict__ vt, unsigned short* __restrict__ attnF)
{
    __shared__ unsigned short v_sw[256 * 128];   // 64 KB, 16B-granule XOR swizzle
    __shared__ unsigned short p_lds[8 * 64 * 8]; // 8 KB
    __shared__ float pmax_s[4][32];
    __shared__ float psum_s[4][32];

    const int t = threadIdx.x;
    const int w = t >> 6;
    const int l = t & 63;
    const int l31 = l & 31;
    const int h = l >> 5;
    const int g = blockIdx.x, b = blockIdx.y;
    const int qbase = g * 32;
    const int c0 = 64 * w;

    const unsigned short* qb = qg + (size_t)b * NN * CRD;
    const unsigned short* kb = kg + (size_t)b * NN * CRD;
    const unsigned short* vb = vt + (size_t)b * CH * NN;

    // resident Q B-frags
    bf16x8 qf0 = *(const bf16x8*)(qb + (size_t)(qbase + l31) * 32 + h * 8);
    bf16x8 qf1 = *(const bf16x8*)(qb + (size_t)(qbase + l31) * 32 + 16 + h * 8);

    // prefetch V granules + K frags for iter 0
    ushort8v vbuf[16];
    #pragma unroll
    for (int j = 0; j < 16; ++j) {
        int gln = t + 256 * j;
        int c = gln >> 4, kgr = gln & 15;
        vbuf[j] = *(const ushort8v*)(vb + (size_t)c * NN + kgr * 8);
    }
    bf16x8 kf0 = *(const bf16x8*)(kb + (size_t)(32 * w + l31) * 32 + h * 8);
    bf16x8 kf1 = *(const bf16x8*)(kb + (size_t)(32 * w + l31) * 32 + 16 + h * 8);

    float m_run = -1e30f, l_run = 0.f;
    floatx16 acc0, acc1;
    #pragma unroll
    for (int i = 0; i < 16; ++i) { acc0[i] = 0.f; acc1[i] = 0.f; }

    for (int it = 0; it < 32; ++it) {
        // ---- phase 0: commit staged V tile (prev PV reads fenced by barrier C) ----
        #pragma unroll
        for (int j = 0; j < 16; ++j) {
            int gln = t + 256 * j;
            int c = gln >> 4, kgr = gln & 15;
            int gi = c * 16 + (kgr ^ (c & 15));
            *(ushort8v*)&v_sw[gi * 8] = vbuf[j];
        }

        // ---- phase 1: scores S[32k][32q] ----
        floatx16 sacc;
        #pragma unroll
        for (int i = 0; i < 16; ++i) sacc[i] = 0.f;
        sacc = __builtin_amdgcn_mfma_f32_32x32x16_bf16(kf0, qf0, sacc, 0, 0, 0);
        sacc = __builtin_amdgcn_mfma_f32_32x32x16_bf16(kf1, qf1, sacc, 0, 0, 0);

        float pm = sacc[0];
        #pragma unroll
        for (int r = 1; r < 16; ++r) pm = fmaxf(pm, sacc[r]);
        pm = fmaxf(pm, __shfl_xor(pm, 32));
        if (h == 0) pmax_s[w][l31] = pm;
        __syncthreads();   // A: V tile committed, pmax visible

        // ---- phase 2: softmax + P->LDS + prefetch next V/K ----
        float mnew = fmaxf(fmaxf(pmax_s[0][l31], pmax_s[1][l31]),
                           fmaxf(pmax_s[2][l31], pmax_s[3][l31]));
        mnew = fmaxf(m_run, mnew);
        float alpha = __expf(m_run - mnew);
        m_run = mnew;
        float pv[16];
        float psum = 0.f;
        #pragma unroll
        for (int r = 0; r < 16; ++r) {
            pv[r] = __expf(sacc[r] - mnew);
            psum += pv[r];
        }
        psum += __shfl_xor(psum, 32);
        if (h == 0) psum_s[w][l31] = psum;
        #pragma unroll
        for (int rg = 0; rg < 4; ++rg) {
            ushort4v pk;
            #pragma unroll
            for (int i = 0; i < 4; ++i) pk[i] = f2bf(pv[rg * 4 + i]);
            int idx = ((2 * w + (rg >> 1)) * 64 + l31 + 32 * (rg & 1)) * 8 + 4 * h;
            *(ushort4v*)&p_lds[idx] = pk;
        }
        if (it < 31) {
            const int k0n = (it + 1) * 128;
            #pragma unroll
            for (int j = 0; j < 16; ++j) {
                int gln = t + 256 * j;
                int c = gln >> 4, kgr = gln & 15;
                vbuf[j] = *(const ushort8v*)(vb + (size_t)c * NN + k0n + kgr * 8);
            }
            kf0 = *(const bf16x8*)(kb + (size_t)(k0n + 32 * w + l31) * 32 + h * 8);
            kf1 = *(const bf16x8*)(kb + (size_t)(k0n + 32 * w + l31) * 32 + 16 + h * 8);
        }
        __syncthreads();   // B: p_lds + psum visible

        // ---- phase 3: PV from swizzled LDS ----
        float isum = (psum_s[0][l31] + psum_s[1][l31]) +
                     (psum_s[2][l31] + psum_s[3][l31]);
        l_run = l_run * alpha + isum;
        #pragma unroll
        for (int i = 0; i < 16; ++i) { acc0[i] *= alpha; acc1[i] *= alpha; }

        const int ca = c0 + l31, cb2 = c0 + 32 + l31;
        #pragma unroll
        for (int s = 0; s < 8; ++s) {
            bf16x8 pf = *(const bf16x8*)&p_lds[(s * 64 + l) * 8];
            bf16x8 va = *(const bf16x8*)&v_sw[(ca * 16 + ((2 * s + h) ^ (ca & 15))) * 8];
            bf16x8 vb3 = *(const bf16x8*)&v_sw[(cb2 * 16 + ((2 * s + h) ^ (cb2 & 15))) * 8];
            acc0 = __builtin_amdgcn_mfma_f32_32x32x16_bf16(va, pf, acc0, 0, 0, 0);
            acc1 = __builtin_amdgcn_mfma_f32_32x32x16_bf16(vb3, pf, acc1, 0, 0, 0);
        }
        __syncthreads();   // C: PV reads done before next commit
    }

    // ---- epilogue: normalize, write frag-major bf16 O ----
    float inv = 1.f / l_run;
    unsigned short* ab = attnF + (size_t)b * CH * NN;
    #pragma unroll
    for (int ct = 0; ct < 2; ++ct) {
        const floatx16& a = ct ? acc1 : acc0;
        #pragma unroll
        for (int rg = 0; rg < 4; ++rg) {
            ushort4v pk;
            #pragma unroll
            for (int i = 0; i < 4; ++i) pk[i] = f2bf(a[rg * 4 + i] * inv);
            int sP = 4 * w + 2 * ct + (rg >> 1);
            size_t idx = ((size_t)(g * 16 + sP) * 64 + l31 + 32 * (rg & 1)) * 8 + 4 * h;
            *(ushort4v*)(ab + idx) = pk;
        }
    }
}

// ---------------------------------------------------------------------------
// K3: Wo GEMM, all operands frag-major (no LDS) + gamma*out + x.
// grid (128 q-tiles, 4 b), block 256 (4 waves; wave w -> o in [64w,64w+64)).
// ---------------------------------------------------------------------------
__global__ __launch_bounds__(256, 2) void out_kernel(
    const unsigned short* __restrict__ attnF, const unsigned short* __restrict__ WobF,
    const float* __restrict__ x, const float* __restrict__ gamma,
    float* __restrict__ out)
{
    const int t = threadIdx.x;
    const int w = t >> 6;
    const int l = t & 63;
    const int l31 = l & 31;
    const int h = l >> 5;
    const int qt = blockIdx.x, b = blockIdx.y;

    const unsigned short* ab = attnF + (size_t)b * CH * NN + (size_t)qt * 16 * 512;

    floatx16 acc[2];
    #pragma unroll
    for (int m = 0; m < 2; ++m)
        #pragma unroll
        for (int i = 0; i < 16; ++i) acc[m][i] = 0.f;

    for (int s = 0; s < 16; ++s) {
        bf16x8 bfr = *(const bf16x8*)(ab + (s * 64 + l) * 8);
        #pragma unroll
        for (int m = 0; m < 2; ++m) {
            int mt = 2 * w + m;
            bf16x8 af = *(const bf16x8*)(WobF + ((size_t)(mt * 16 + s) * 64 + l) * 8);
            acc[m] = __builtin_amdgcn_mfma_f32_32x32x16_bf16(af, bfr, acc[m], 0, 0, 0);
        }
    }

    const float gm = gamma[0];
    #pragma unroll
    for (int m = 0; m < 2; ++m)
        #pragma unroll
        for (int r = 0; r < 16; ++r) {
            int o = (2 * w + m) * 32 + (r & 3) + 8 * (r >> 2) + 4 * h;
            int n = qt * 32 + l31;
            size_t oi = ((size_t)(b * 256 + o)) * NN + n;
            out[oi] = gm * acc[m][r] + x[oi];
        }
}

// ---------------------------------------------------------------------------
extern "C" void kernel_launch(void* const* d_in, const int* in_sizes, int n_in,
                              void* d_out, int out_size, void* d_ws, size_t ws_size,
                              hipStream_t stream)
{
    const float* x     = (const float*)d_in[0];
    const float* Wq    = (const float*)d_in[1];
    const float* Wk    = (const float*)d_in[2];
    const float* Wv    = (const float*)d_in[3];
    const float* Wo    = (const float*)d_in[4];
    const float* gamma = (const float*)d_in[5];
    float* out = (float*)d_out;

    char* wsb = (char*)d_ws;
    unsigned short* q     = (unsigned short*)(wsb);                          // 1 MB
    unsigned short* k     = (unsigned short*)(wsb + (1u << 20));             // 1 MB
    unsigned short* vt    = (unsigned short*)(wsb + (2u << 20));             // 8 MB
    float*          Wt2   = (float*)         (wsb + (10u << 20));            // 320 KB
    unsigned short* WobF  = (unsigned short*)(wsb + (10u << 20) + (320u << 10)); // 128 KB
    unsigned short* attnF = (unsigned short*)(wsb + (11u << 20));            // 8 MB

    wconv_kernel<<<320, 256, 0, stream>>>(Wq, Wk, Wv, Wo, Wt2, WobF);

    dim3 g1(16, 10, BATCH);
    qkv_kernel<<<g1, 256, 0, stream>>>(x, Wt2, q, k, vt);

    dim3 g2(128, BATCH);
    attn_kernel<<<g2, 256, 0, stream>>>(q, k, vt, attnF);

    dim3 g3(128, BATCH);
    out_kernel<<<g3, 256, 0, stream>>>(attnF, WobF, x, gamma, out);
}

// Round 6
// 198.083 us; speedup vs baseline: 3.5085x; 1.2443x over previous
//
#include <hip/hip_runtime.h>
#include <hip/hip_bf16.h>

#define BATCH 4
#define CH 256
#define CRD 32
#define NN 4096

typedef __bf16 bf16x8 __attribute__((ext_vector_type(8)));
typedef float floatx4 __attribute__((ext_vector_type(4)));
typedef float floatx16 __attribute__((ext_vector_type(16)));
typedef unsigned short ushort4v __attribute__((ext_vector_type(4)));
typedef unsigned short ushort8v __attribute__((ext_vector_type(8)));

static __device__ __forceinline__ unsigned short f2bf(float f) {
    unsigned int u = __float_as_uint(f);
    u += 0x7fff + ((u >> 16) & 1);           // RNE
    return (unsigned short)(u >> 16);
}

// ---------------------------------------------------------------------------
// Fragment layout conventions (32x32x16 bf16 MFMA), verified by R2-R5 passing:
//   A[m][k]: lane l holds m = l&31, k = (l>>5)*8 + j
//   B[k][n]: lane l holds n = l&31, k = (l>>5)*8 + j
//   D      : lane l holds col = l&31, row = (r&3) + 8*(r>>2) + 4*(l>>5)
// Frag-major storage of a matrix M[dim32][dim16] as tiles:
//   addr = (tile_linear*64 + (dim32_idx&31) + 32*((dim16_idx>>3)&1))*8 + (dim16_idx&7)
// Both A-frag and B-frag reads from this storage are lane-linear b128 loads.
// ---------------------------------------------------------------------------

// ---------------------------------------------------------------------------
// K0: weight prep. What: [mb 0..9][kblk 0..15] A-frag-major QKV weights
// (mb0 = Wq pre-scaled, mb1 = Wk, mb2-9 = Wv). WobF: same for Wo.
// grid 320 x 256.
// ---------------------------------------------------------------------------
__global__ __launch_bounds__(256) void wconv_kernel(
    const float* __restrict__ Wq, const float* __restrict__ Wk,
    const float* __restrict__ Wv, const float* __restrict__ Wo,
    unsigned short* __restrict__ What, unsigned short* __restrict__ WobF)
{
    const int o = blockIdx.x;
    const int t = threadIdx.x;   // input channel c
    float scale = 1.0f;
    const float* src;
    if (o < 32)      { src = Wq + o * 256; scale = 0.17677669529663687f; }
    else if (o < 64) { src = Wk + (o - 32) * 256; }
    else             { src = Wv + (o - 64) * 256; }
    const int mb = o >> 5;
    const size_t idx = ((size_t)(mb * 16 + (t >> 4)) * 64
                        + (o & 31) + 32 * ((t >> 3) & 1)) * 8 + (t & 7);
    What[idx] = f2bf(src[t] * scale);
    if (o < 256) {
        const size_t i2 = ((size_t)((o >> 5) * 16 + (t >> 4)) * 64
                           + (o & 31) + 32 * ((t >> 3) & 1)) * 8 + (t & 7);
        WobF[i2] = f2bf(Wo[o * 256 + t]);
    }
}

// ---------------------------------------------------------------------------
// K1: QKV as MFMA GEMM. grid (128 n-tiles of 32, 4 b), block 256 (4 waves).
// Stage x-tile [256c][32n] f32->bf16 into LDS frag-major, 16 K-steps.
// Wave w owns output m-blocks {w, w+4} and (w<2) ? {w+8}.
// Outputs: qh/kh frag-major [b][nt][kblk 2][64][8]; vh [b][cblk 8][kf 256][64][8].
// ---------------------------------------------------------------------------
__global__ __launch_bounds__(256, 2) void qkv_kernel(
    const float* __restrict__ x, const unsigned short* __restrict__ What,
    unsigned short* __restrict__ qh, unsigned short* __restrict__ kh,
    unsigned short* __restrict__ vh)
{
    __shared__ unsigned short xf[16 * 512];   // 16 KB, frag-major x tile

    const int t = threadIdx.x;
    const int w = t >> 6;
    const int l = t & 63;
    const int l31 = l & 31;
    const int h = l >> 5;
    const int nt = blockIdx.x, b = blockIdx.y;
    const int n0 = nt * 32;

    // ---- stage: 8 passes, 32 c-rows x 32 n each (coalesced 128B rows) ----
    {
        const float* xb = x + (size_t)(b * CH) * NN + n0;
        const int cr = t >> 3;          // 0..31
        const int nc = (t & 7) * 4;     // 0..28
        #pragma unroll
        for (int p = 0; p < 8; ++p) {
            int c = p * 32 + cr;
            floatx4 v4 = *(const floatx4*)(xb + (size_t)c * NN + nc);
            int base = (c >> 4) * 512 + 32 * ((c >> 3) & 1) * 8 + (c & 7);
            xf[base + (nc + 0) * 8] = f2bf(v4[0]);
            xf[base + (nc + 1) * 8] = f2bf(v4[1]);
            xf[base + (nc + 2) * 8] = f2bf(v4[2]);
            xf[base + (nc + 3) * 8] = f2bf(v4[3]);
        }
    }
    __syncthreads();

    const int mb0 = w, mb1 = w + 4, mb2 = w + 8;   // mb2 valid only for w<2
    floatx16 acc0, acc1, acc2;
    #pragma unroll
    for (int i = 0; i < 16; ++i) { acc0[i] = 0.f; acc1[i] = 0.f; acc2[i] = 0.f; }

    for (int kblk = 0; kblk < 16; ++kblk) {
        bf16x8 bf = *(const bf16x8*)&xf[kblk * 512 + l * 8];
        bf16x8 a0 = *(const bf16x8*)(What + ((size_t)(mb0 * 16 + kblk) * 64 + l) * 8);
        bf16x8 a1 = *(const bf16x8*)(What + ((size_t)(mb1 * 16 + kblk) * 64 + l) * 8);
        acc0 = __builtin_amdgcn_mfma_f32_32x32x16_bf16(a0, bf, acc0, 0, 0, 0);
        acc1 = __builtin_amdgcn_mfma_f32_32x32x16_bf16(a1, bf, acc1, 0, 0, 0);
        if (w < 2) {
            bf16x8 a2 = *(const bf16x8*)(What + ((size_t)(mb2 * 16 + kblk) * 64 + l) * 8);
            acc2 = __builtin_amdgcn_mfma_f32_32x32x16_bf16(a2, bf, acc2, 0, 0, 0);
        }
    }

    // ---- epilogue: scatter 2B stores into frag-major outputs ----
    auto store_qk = [&](unsigned short* dst, const floatx16& a) {
        size_t base = (size_t)(b * 128 + nt) * 1024;
        #pragma unroll
        for (int r = 0; r < 16; ++r) {
            int rowo = (r & 3) + 8 * (r >> 2) + 4 * h;
            size_t idx = base + (size_t)(rowo >> 4) * 512
                         + (size_t)(l31 + 32 * ((rowo >> 3) & 1)) * 8 + (rowo & 7);
            dst[idx] = f2bf(a[r]);
        }
    };
    auto store_v = [&](int cblk, const floatx16& a) {
        size_t base = (((size_t)b * 8 + cblk) * 256 + nt * 2 + (l31 >> 4)) * 512
                      + 32 * ((l31 >> 3) & 1) * 8 + (l31 & 7);
        #pragma unroll
        for (int r = 0; r < 16; ++r) {
            int rowo = (r & 3) + 8 * (r >> 2) + 4 * h;
            vh[base + rowo * 8] = f2bf(a[r]);
        }
    };

    if (w == 0)      store_qk(qh, acc0);
    else if (w == 1) store_qk(kh, acc0);
    else             store_v(w - 2, acc0);     // mb 2,3 -> cblk 0,1
    store_v(w + 2, acc1);                       // mb 4..7 -> cblk 2..5
    if (w < 2) store_v(w + 6, acc2);            // mb 8,9 -> cblk 6,7
}

// ---------------------------------------------------------------------------
// K2: flash attention, all Q/K/V fragments read directly from frag-major
// global buffers (coalesced 1KB wave-loads, L2-resident). No V LDS.
// grid (128 q-tiles of 32, 4 b), block 256 (4 waves), 2 barriers/iter.
// Wave w: score key-slice [32w,+32); PV channels cblk {2w, 2w+1}.
// Output: normalized bf16 O in K3-B-frag-major order.
// ---------------------------------------------------------------------------
__global__ __launch_bounds__(256, 2) void attn_kernel(
    const unsigned short* __restrict__ qh, const unsigned short* __restrict__ kh,
    const unsigned short* __restrict__ vh, unsigned short* __restrict__ attnF)
{
    __shared__ unsigned short p_lds[8 * 64 * 8];   // 8 KB, frag-major P
    __shared__ float pmax_s[4][32];
    __shared__ float psum_s[4][32];

    const int t = threadIdx.x;
    const int w = t >> 6;
    const int l = t & 63;
    const int l31 = l & 31;
    const int h = l >> 5;
    const int g = blockIdx.x, b = blockIdx.y;

    const unsigned short* qB = qh + (size_t)(b * 128 + g) * 1024;
    const unsigned short* kB = kh + (size_t)b * 128 * 1024;
    const unsigned short* vB = vh + (size_t)b * 8 * 256 * 512;

    // resident Q B-frags
    bf16x8 qf0 = *(const bf16x8*)(qB + l * 8);
    bf16x8 qf1 = *(const bf16x8*)(qB + 512 + l * 8);

    // prefetch K A-frags for iter 0
    bf16x8 kf0 = *(const bf16x8*)(kB + (size_t)w * 1024 + l * 8);
    bf16x8 kf1 = *(const bf16x8*)(kB + (size_t)w * 1024 + 512 + l * 8);

    float m_run = -1e30f, l_run = 0.f;
    floatx16 acc0, acc1;
    #pragma unroll
    for (int i = 0; i < 16; ++i) { acc0[i] = 0.f; acc1[i] = 0.f; }

    for (int it = 0; it < 32; ++it) {
        // ---- phase 1: scores S[32k][32q] for this wave's key slice ----
        floatx16 sacc;
        #pragma unroll
        for (int i = 0; i < 16; ++i) sacc[i] = 0.f;
        sacc = __builtin_amdgcn_mfma_f32_32x32x16_bf16(kf0, qf0, sacc, 0, 0, 0);
        sacc = __builtin_amdgcn_mfma_f32_32x32x16_bf16(kf1, qf1, sacc, 0, 0, 0);

        float pm = sacc[0];
        #pragma unroll
        for (int r = 1; r < 16; ++r) pm = fmaxf(pm, sacc[r]);
        pm = fmaxf(pm, __shfl_xor(pm, 32));
        if (h == 0) pmax_s[w][l31] = pm;
        __syncthreads();   // A: pmax visible; prev-iter p_lds reads done

        // ---- phase 2: online softmax, P -> LDS, prefetch next K ----
        float mnew = fmaxf(fmaxf(pmax_s[0][l31], pmax_s[1][l31]),
                           fmaxf(pmax_s[2][l31], pmax_s[3][l31]));
        mnew = fmaxf(m_run, mnew);
        float alpha = __expf(m_run - mnew);
        m_run = mnew;
        float pv[16];
        float psum = 0.f;
        #pragma unroll
        for (int r = 0; r < 16; ++r) {
            pv[r] = __expf(sacc[r] - mnew);
            psum += pv[r];
        }
        psum += __shfl_xor(psum, 32);
        if (h == 0) psum_s[w][l31] = psum;
        #pragma unroll
        for (int rg = 0; rg < 4; ++rg) {
            ushort4v pk;
            #pragma unroll
            for (int i = 0; i < 4; ++i) pk[i] = f2bf(pv[rg * 4 + i]);
            int idx = ((2 * w + (rg >> 1)) * 64 + l31 + 32 * (rg & 1)) * 8 + 4 * h;
            *(ushort4v*)&p_lds[idx] = pk;
        }
        if (it < 31) {
            const unsigned short* kn = kB + (size_t)((it + 1) * 4 + w) * 1024;
            kf0 = *(const bf16x8*)(kn + l * 8);
            kf1 = *(const bf16x8*)(kn + 512 + l * 8);
        }
        __syncthreads();   // B: p_lds + psum visible

        // ---- phase 3: rescale + PV from global V frags (depth-2 pipeline) ----
        float isum = (psum_s[0][l31] + psum_s[1][l31]) +
                     (psum_s[2][l31] + psum_s[3][l31]);
        l_run = l_run * alpha + isum;
        #pragma unroll
        for (int i = 0; i < 16; ++i) { acc0[i] *= alpha; acc1[i] *= alpha; }

        const unsigned short* v0b = vB + ((size_t)(2 * w) * 256 + it * 8) * 512;
        const unsigned short* v1b = vB + ((size_t)(2 * w + 1) * 256 + it * 8) * 512;
        bf16x8 va = *(const bf16x8*)(v0b + l * 8);
        bf16x8 vc = *(const bf16x8*)(v1b + l * 8);
        bf16x8 pf = *(const bf16x8*)&p_lds[l * 8];
        #pragma unroll
        for (int s = 0; s < 8; ++s) {
            bf16x8 va_n, vc_n, pf_n;
            if (s < 7) {
                va_n = *(const bf16x8*)(v0b + (s + 1) * 512 + l * 8);
                vc_n = *(const bf16x8*)(v1b + (s + 1) * 512 + l * 8);
                pf_n = *(const bf16x8*)&p_lds[((s + 1) * 64 + l) * 8];
            }
            acc0 = __builtin_amdgcn_mfma_f32_32x32x16_bf16(va, pf, acc0, 0, 0, 0);
            acc1 = __builtin_amdgcn_mfma_f32_32x32x16_bf16(vc, pf, acc1, 0, 0, 0);
            va = va_n; vc = vc_n; pf = pf_n;
        }
    }

    // ---- epilogue: normalize, write frag-major bf16 O ----
    float inv = 1.f / l_run;
    unsigned short* ab = attnF + (size_t)b * CH * NN;
    #pragma unroll
    for (int ct = 0; ct < 2; ++ct) {
        const floatx16& a = ct ? acc1 : acc0;
        #pragma unroll
        for (int rg = 0; rg < 4; ++rg) {
            ushort4v pk;
            #pragma unroll
            for (int i = 0; i < 4; ++i) pk[i] = f2bf(a[rg * 4 + i] * inv);
            int sP = 4 * w + 2 * ct + (rg >> 1);
            size_t idx = ((size_t)(g * 16 + sP) * 64 + l31 + 32 * (rg & 1)) * 8 + 4 * h;
            *(ushort4v*)(ab + idx) = pk;
        }
    }
}

// ---------------------------------------------------------------------------
// K3: Wo GEMM, all operands frag-major (no LDS) + gamma*out + x.
// grid (128 q-tiles, 4 b), block 256 (4 waves; wave w -> o in [64w,64w+64)).
// ---------------------------------------------------------------------------
__global__ __launch_bounds__(256, 2) void out_kernel(
    const unsigned short* __restrict__ attnF, const unsigned short* __restrict__ WobF,
    const float* __restrict__ x, const float* __restrict__ gamma,
    float* __restrict__ out)
{
    const int t = threadIdx.x;
    const int w = t >> 6;
    const int l = t & 63;
    const int l31 = l & 31;
    const int h = l >> 5;
    const int qt = blockIdx.x, b = blockIdx.y;

    const unsigned short* ab = attnF + (size_t)b * CH * NN + (size_t)qt * 16 * 512;

    floatx16 acc[2];
    #pragma unroll
    for (int m = 0; m < 2; ++m)
        #pragma unroll
        for (int i = 0; i < 16; ++i) acc[m][i] = 0.f;

    for (int s = 0; s < 16; ++s) {
        bf16x8 bfr = *(const bf16x8*)(ab + (s * 64 + l) * 8);
        #pragma unroll
        for (int m = 0; m < 2; ++m) {
            int mt = 2 * w + m;
            bf16x8 af = *(const bf16x8*)(WobF + ((size_t)(mt * 16 + s) * 64 + l) * 8);
            acc[m] = __builtin_amdgcn_mfma_f32_32x32x16_bf16(af, bfr, acc[m], 0, 0, 0);
        }
    }

    const float gm = gamma[0];
    #pragma unroll
    for (int m = 0; m < 2; ++m)
        #pragma unroll
        for (int r = 0; r < 16; ++r) {
            int o = (2 * w + m) * 32 + (r & 3) + 8 * (r >> 2) + 4 * h;
            int n = qt * 32 + l31;
            size_t oi = ((size_t)(b * 256 + o)) * NN + n;
            out[oi] = gm * acc[m][r] + x[oi];
        }
}

// ---------------------------------------------------------------------------
extern "C" void kernel_launch(void* const* d_in, const int* in_sizes, int n_in,
                              void* d_out, int out_size, void* d_ws, size_t ws_size,
                              hipStream_t stream)
{
    const float* x     = (const float*)d_in[0];
    const float* Wq    = (const float*)d_in[1];
    const float* Wk    = (const float*)d_in[2];
    const float* Wv    = (const float*)d_in[3];
    const float* Wo    = (const float*)d_in[4];
    const float* gamma = (const float*)d_in[5];
    float* out = (float*)d_out;

    char* wsb = (char*)d_ws;
    unsigned short* qh    = (unsigned short*)(wsb);                          // 1 MB
    unsigned short* kh    = (unsigned short*)(wsb + (1u << 20));             // 1 MB
    unsigned short* vh    = (unsigned short*)(wsb + (2u << 20));             // 8 MB
    unsigned short* What  = (unsigned short*)(wsb + (10u << 20));            // 160 KB
    unsigned short* WobF  = (unsigned short*)(wsb + (10u << 20) + (256u << 10)); // 128 KB
    unsigned short* attnF = (unsigned short*)(wsb + (11u << 20));            // 8 MB

    wconv_kernel<<<320, 256, 0, stream>>>(Wq, Wk, Wv, Wo, What, WobF);

    dim3 g1(128, BATCH);
    qkv_kernel<<<g1, 256, 0, stream>>>(x, What, qh, kh, vh);

    dim3 g2(128, BATCH);
    attn_kernel<<<g2, 256, 0, stream>>>(qh, kh, vh, attnF);

    dim3 g3(128, BATCH);
    out_kernel<<<g3, 256, 0, stream>>>(attnF, WobF, x, gamma, out);
}

// Round 7
// 164.666 us; speedup vs baseline: 4.2205x; 1.2029x over previous
//
#include <hip/hip_runtime.h>
#include <hip/hip_bf16.h>

#define BATCH 4
#define CH 256
#define CRD 32
#define NN 4096

typedef __bf16 bf16x8 __attribute__((ext_vector_type(8)));
typedef float floatx4 __attribute__((ext_vector_type(4)));
typedef float floatx16 __attribute__((ext_vector_type(16)));
typedef unsigned short ushort4v __attribute__((ext_vector_type(4)));
typedef unsigned short ushort8v __attribute__((ext_vector_type(8)));

static __device__ __forceinline__ unsigned short f2bf(float f) {
    unsigned int u = __float_as_uint(f);
    u += 0x7fff + ((u >> 16) & 1);           // RNE
    return (unsigned short)(u >> 16);
}
static __device__ __forceinline__ float bf2f(unsigned short h) {
    return __uint_as_float((unsigned int)h << 16);
}

// ---------------------------------------------------------------------------
// Fragment layout conventions (32x32x16 bf16 MFMA), verified R2-R6:
//   A[m][k]: lane l holds m = l&31, k = (l>>5)*8 + j
//   B[k][n]: lane l holds n = l&31, k = (l>>5)*8 + j
//   D      : lane l holds col = l&31, row = (r&3) + 8*(r>>2) + 4*(l>>5)
// Frag-major storage: addr = (tile*64 + (d32&31) + 32*((d16>>3)&1))*8 + (d16&7)
// => both A-frag and B-frag reads are lane-linear b128 loads.
// ---------------------------------------------------------------------------

// ---------------------------------------------------------------------------
// K0: weight prep. What: [mb 0..9][kblk 0..15] A-frag-major QKV weights
// (mb0 = Wq pre-scaled, mb1 = Wk, mb2-9 = Wv). WobF: same for Wo.
// grid 320 x 256.
// ---------------------------------------------------------------------------
__global__ __launch_bounds__(256) void wconv_kernel(
    const float* __restrict__ Wq, const float* __restrict__ Wk,
    const float* __restrict__ Wv, const float* __restrict__ Wo,
    unsigned short* __restrict__ What, unsigned short* __restrict__ WobF)
{
    const int o = blockIdx.x;
    const int t = threadIdx.x;   // input channel c
    float scale = 1.0f;
    const float* src;
    if (o < 32)      { src = Wq + o * 256; scale = 0.17677669529663687f; }
    else if (o < 64) { src = Wk + (o - 32) * 256; }
    else             { src = Wv + (o - 64) * 256; }
    const int mb = o >> 5;
    const size_t idx = ((size_t)(mb * 16 + (t >> 4)) * 64
                        + (o & 31) + 32 * ((t >> 3) & 1)) * 8 + (t & 7);
    What[idx] = f2bf(src[t] * scale);
    if (o < 256) {
        const size_t i2 = ((size_t)((o >> 5) * 16 + (t >> 4)) * 64
                           + (o & 31) + 32 * ((t >> 3) & 1)) * 8 + (t & 7);
        WobF[i2] = f2bf(Wo[o * 256 + t]);
    }
}

// ---------------------------------------------------------------------------
// K1: QKV as MFMA GEMM. grid (128 n-tiles of 32, 4 b), block 256 (4 waves).
// Outputs: qh/kh frag-major [b][nt][kblk 2][64][8]; vh [b][cblk 8][kf 256][64][8].
// ---------------------------------------------------------------------------
__global__ __launch_bounds__(256, 2) void qkv_kernel(
    const float* __restrict__ x, const unsigned short* __restrict__ What,
    unsigned short* __restrict__ qh, unsigned short* __restrict__ kh,
    unsigned short* __restrict__ vh)
{
    __shared__ unsigned short xf[16 * 512];   // 16 KB, frag-major x tile

    const int t = threadIdx.x;
    const int w = t >> 6;
    const int l = t & 63;
    const int l31 = l & 31;
    const int h = l >> 5;
    const int nt = blockIdx.x, b = blockIdx.y;
    const int n0 = nt * 32;

    {
        const float* xb = x + (size_t)(b * CH) * NN + n0;
        const int cr = t >> 3;          // 0..31
        const int nc = (t & 7) * 4;     // 0..28
        #pragma unroll
        for (int p = 0; p < 8; ++p) {
            int c = p * 32 + cr;
            floatx4 v4 = *(const floatx4*)(xb + (size_t)c * NN + nc);
            int base = (c >> 4) * 512 + 32 * ((c >> 3) & 1) * 8 + (c & 7);
            xf[base + (nc + 0) * 8] = f2bf(v4[0]);
            xf[base + (nc + 1) * 8] = f2bf(v4[1]);
            xf[base + (nc + 2) * 8] = f2bf(v4[2]);
            xf[base + (nc + 3) * 8] = f2bf(v4[3]);
        }
    }
    __syncthreads();

    const int mb0 = w, mb1 = w + 4, mb2 = w + 8;   // mb2 valid only for w<2
    floatx16 acc0, acc1, acc2;
    #pragma unroll
    for (int i = 0; i < 16; ++i) { acc0[i] = 0.f; acc1[i] = 0.f; acc2[i] = 0.f; }

    for (int kblk = 0; kblk < 16; ++kblk) {
        bf16x8 bf = *(const bf16x8*)&xf[kblk * 512 + l * 8];
        bf16x8 a0 = *(const bf16x8*)(What + ((size_t)(mb0 * 16 + kblk) * 64 + l) * 8);
        bf16x8 a1 = *(const bf16x8*)(What + ((size_t)(mb1 * 16 + kblk) * 64 + l) * 8);
        acc0 = __builtin_amdgcn_mfma_f32_32x32x16_bf16(a0, bf, acc0, 0, 0, 0);
        acc1 = __builtin_amdgcn_mfma_f32_32x32x16_bf16(a1, bf, acc1, 0, 0, 0);
        if (w < 2) {
            bf16x8 a2 = *(const bf16x8*)(What + ((size_t)(mb2 * 16 + kblk) * 64 + l) * 8);
            acc2 = __builtin_amdgcn_mfma_f32_32x32x16_bf16(a2, bf, acc2, 0, 0, 0);
        }
    }

    auto store_qk = [&](unsigned short* dst, const floatx16& a) {
        size_t base = (size_t)(b * 128 + nt) * 1024;
        #pragma unroll
        for (int r = 0; r < 16; ++r) {
            int rowo = (r & 3) + 8 * (r >> 2) + 4 * h;
            size_t idx = base + (size_t)(rowo >> 4) * 512
                         + (size_t)(l31 + 32 * ((rowo >> 3) & 1)) * 8 + (rowo & 7);
            dst[idx] = f2bf(a[r]);
        }
    };
    auto store_v = [&](int cblk, const floatx16& a) {
        size_t base = (((size_t)b * 8 + cblk) * 256 + nt * 2 + (l31 >> 4)) * 512
                      + 32 * ((l31 >> 3) & 1) * 8 + (l31 & 7);
        #pragma unroll
        for (int r = 0; r < 16; ++r) {
            int rowo = (r & 3) + 8 * (r >> 2) + 4 * h;
            vh[base + rowo * 8] = f2bf(a[r]);
        }
    };

    if (w == 0)      store_qk(qh, acc0);
    else if (w == 1) store_qk(kh, acc0);
    else             store_v(w - 2, acc0);
    store_v(w + 2, acc1);
    if (w < 2) store_v(w + 6, acc2);
}

// ---------------------------------------------------------------------------
// K2: flash attention, key-split 2 for occupancy (4 blocks/CU).
// grid (128 q-tiles of 32, 2 key-splits, 4 b), block 256 (4 waves).
// Wave w: score key-slice [32w,+32); PV channels cblk {2w, 2w+1}.
// Writes UNNORMALIZED bf16 O-partials (K3-B-frag-major per (b,g,ks)) + (m,l).
// ---------------------------------------------------------------------------
__global__ __launch_bounds__(256, 4) void attn_kernel(
    const unsigned short* __restrict__ qh, const unsigned short* __restrict__ kh,
    const unsigned short* __restrict__ vh, unsigned short* __restrict__ Opart,
    float* __restrict__ ml)
{
    __shared__ unsigned short p_lds[8 * 64 * 8];   // 8 KB, frag-major P
    __shared__ float pmax_s[4][32];
    __shared__ float psum_s[4][32];

    const int t = threadIdx.x;
    const int w = t >> 6;
    const int l = t & 63;
    const int l31 = l & 31;
    const int h = l >> 5;
    const int g = blockIdx.x, ks = blockIdx.y, b = blockIdx.z;

    const unsigned short* qB = qh + (size_t)(b * 128 + g) * 1024;
    const unsigned short* kB = kh + (size_t)b * 128 * 1024;
    const unsigned short* vB = vh + (size_t)b * 8 * 256 * 512;

    // resident Q B-frags
    bf16x8 qf0 = *(const bf16x8*)(qB + l * 8);
    bf16x8 qf1 = *(const bf16x8*)(qB + 512 + l * 8);

    // prefetch K A-frags for iter 0
    bf16x8 kf0 = *(const bf16x8*)(kB + (size_t)(ks * 64 + w) * 1024 + l * 8);
    bf16x8 kf1 = *(const bf16x8*)(kB + (size_t)(ks * 64 + w) * 1024 + 512 + l * 8);

    float m_run = -1e30f, l_run = 0.f;
    floatx16 acc0, acc1;
    #pragma unroll
    for (int i = 0; i < 16; ++i) { acc0[i] = 0.f; acc1[i] = 0.f; }

    for (int it = 0; it < 16; ++it) {
        // ---- phase 1: scores S[32k][32q] for this wave's key slice ----
        floatx16 sacc;
        #pragma unroll
        for (int i = 0; i < 16; ++i) sacc[i] = 0.f;
        sacc = __builtin_amdgcn_mfma_f32_32x32x16_bf16(kf0, qf0, sacc, 0, 0, 0);
        sacc = __builtin_amdgcn_mfma_f32_32x32x16_bf16(kf1, qf1, sacc, 0, 0, 0);

        float pm = sacc[0];
        #pragma unroll
        for (int r = 1; r < 16; ++r) pm = fmaxf(pm, sacc[r]);
        pm = fmaxf(pm, __shfl_xor(pm, 32));
        if (h == 0) pmax_s[w][l31] = pm;
        __syncthreads();   // A: pmax visible; prev-iter p_lds reads done

        // ---- phase 2: online softmax, P -> LDS, prefetch next K ----
        float mnew = fmaxf(fmaxf(pmax_s[0][l31], pmax_s[1][l31]),
                           fmaxf(pmax_s[2][l31], pmax_s[3][l31]));
        mnew = fmaxf(m_run, mnew);
        float alpha = __expf(m_run - mnew);
        m_run = mnew;
        float pv[16];
        float psum = 0.f;
        #pragma unroll
        for (int r = 0; r < 16; ++r) {
            pv[r] = __expf(sacc[r] - mnew);
            psum += pv[r];
        }
        psum += __shfl_xor(psum, 32);
        if (h == 0) psum_s[w][l31] = psum;
        #pragma unroll
        for (int rg = 0; rg < 4; ++rg) {
            ushort4v pk;
            #pragma unroll
            for (int i = 0; i < 4; ++i) pk[i] = f2bf(pv[rg * 4 + i]);
            int idx = ((2 * w + (rg >> 1)) * 64 + l31 + 32 * (rg & 1)) * 8 + 4 * h;
            *(ushort4v*)&p_lds[idx] = pk;
        }
        if (it < 15) {
            const unsigned short* kn = kB + (size_t)(ks * 64 + (it + 1) * 4 + w) * 1024;
            kf0 = *(const bf16x8*)(kn + l * 8);
            kf1 = *(const bf16x8*)(kn + 512 + l * 8);
        }
        __syncthreads();   // B: p_lds + psum visible

        // ---- phase 3: rescale + PV from global V frags (depth-2 pipeline) ----
        float isum = (psum_s[0][l31] + psum_s[1][l31]) +
                     (psum_s[2][l31] + psum_s[3][l31]);
        l_run = l_run * alpha + isum;
        #pragma unroll
        for (int i = 0; i < 16; ++i) { acc0[i] *= alpha; acc1[i] *= alpha; }

        const unsigned short* v0b = vB + ((size_t)(2 * w) * 256 + (ks * 16 + it) * 8) * 512;
        const unsigned short* v1b = vB + ((size_t)(2 * w + 1) * 256 + (ks * 16 + it) * 8) * 512;
        bf16x8 va = *(const bf16x8*)(v0b + l * 8);
        bf16x8 vc = *(const bf16x8*)(v1b + l * 8);
        bf16x8 pf = *(const bf16x8*)&p_lds[l * 8];
        #pragma unroll
        for (int s = 0; s < 8; ++s) {
            bf16x8 va_n, vc_n, pf_n;
            if (s < 7) {
                va_n = *(const bf16x8*)(v0b + (s + 1) * 512 + l * 8);
                vc_n = *(const bf16x8*)(v1b + (s + 1) * 512 + l * 8);
                pf_n = *(const bf16x8*)&p_lds[((s + 1) * 64 + l) * 8];
            }
            acc0 = __builtin_amdgcn_mfma_f32_32x32x16_bf16(va, pf, acc0, 0, 0, 0);
            acc1 = __builtin_amdgcn_mfma_f32_32x32x16_bf16(vc, pf, acc1, 0, 0, 0);
            va = va_n; vc = vc_n; pf = pf_n;
        }
    }

    // ---- epilogue: write unnormalized frag-major bf16 O-partial + (m,l) ----
    unsigned short* op = Opart + ((size_t)((b * 128 + g) * 2 + ks)) * 8192;
    #pragma unroll
    for (int ct = 0; ct < 2; ++ct) {
        const floatx16& a = ct ? acc1 : acc0;
        #pragma unroll
        for (int rg = 0; rg < 4; ++rg) {
            ushort4v pk;
            #pragma unroll
            for (int i = 0; i < 4; ++i) pk[i] = f2bf(a[rg * 4 + i]);
            int sP = 4 * w + 2 * ct + (rg >> 1);
            size_t idx = ((size_t)sP * 64 + l31 + 32 * (rg & 1)) * 8 + 4 * h;
            *(ushort4v*)(op + idx) = pk;
        }
    }
    if (w == 0 && h == 0) {
        size_t mb = ((size_t)(b * 128 + g) * 2 + ks) * 64;
        ml[mb + l31] = m_run;
        ml[mb + 32 + l31] = l_run;
    }
}

// ---------------------------------------------------------------------------
// K3: combine 2 key-split partials (registers) + Wo GEMM + gamma*out + x.
// grid (128 q-tiles, 4 b), block 256 (4 waves; wave w -> o in [64w,64w+64)).
// ---------------------------------------------------------------------------
__global__ __launch_bounds__(256, 2) void out_kernel(
    const unsigned short* __restrict__ Opart, const float* __restrict__ ml,
    const unsigned short* __restrict__ WobF, const float* __restrict__ x,
    const float* __restrict__ gamma, float* __restrict__ out)
{
    const int t = threadIdx.x;
    const int w = t >> 6;
    const int l = t & 63;
    const int l31 = l & 31;
    const int h = l >> 5;
    const int qt = blockIdx.x, b = blockIdx.y;

    // per-lane combine weights for query q = l31
    const size_t mb = (size_t)(b * 128 + qt) * 2 * 64;
    float m0 = ml[mb + l31],       l0 = ml[mb + 32 + l31];
    float m1 = ml[mb + 64 + l31],  l1 = ml[mb + 96 + l31];
    float M  = fmaxf(m0, m1);
    float e0 = __expf(m0 - M), e1 = __expf(m1 - M);
    float Lc = l0 * e0 + l1 * e1;
    float w0 = e0 / Lc, w1 = e1 / Lc;

    const unsigned short* o0 = Opart + ((size_t)(b * 128 + qt) * 2 + 0) * 8192;
    const unsigned short* o1 = Opart + ((size_t)(b * 128 + qt) * 2 + 1) * 8192;

    floatx16 acc[2];
    #pragma unroll
    for (int m = 0; m < 2; ++m)
        #pragma unroll
        for (int i = 0; i < 16; ++i) acc[m][i] = 0.f;

    for (int s = 0; s < 16; ++s) {
        ushort8v f0 = *(const ushort8v*)(o0 + (s * 64 + l) * 8);
        ushort8v f1 = *(const ushort8v*)(o1 + (s * 64 + l) * 8);
        ushort8v cmb;
        #pragma unroll
        for (int j = 0; j < 8; ++j)
            cmb[j] = f2bf(w0 * bf2f(f0[j]) + w1 * bf2f(f1[j]));
        bf16x8 bfr = *(bf16x8*)&cmb;
        #pragma unroll
        for (int m = 0; m < 2; ++m) {
            int mt = 2 * w + m;
            bf16x8 af = *(const bf16x8*)(WobF + ((size_t)(mt * 16 + s) * 64 + l) * 8);
            acc[m] = __builtin_amdgcn_mfma_f32_32x32x16_bf16(af, bfr, acc[m], 0, 0, 0);
        }
    }

    const float gm = gamma[0];
    #pragma unroll
    for (int m = 0; m < 2; ++m)
        #pragma unroll
        for (int r = 0; r < 16; ++r) {
            int o = (2 * w + m) * 32 + (r & 3) + 8 * (r >> 2) + 4 * h;
            int n = qt * 32 + l31;
            size_t oi = ((size_t)(b * 256 + o)) * NN + n;
            out[oi] = gm * acc[m][r] + x[oi];
        }
}

// ---------------------------------------------------------------------------
extern "C" void kernel_launch(void* const* d_in, const int* in_sizes, int n_in,
                              void* d_out, int out_size, void* d_ws, size_t ws_size,
                              hipStream_t stream)
{
    const float* x     = (const float*)d_in[0];
    const float* Wq    = (const float*)d_in[1];
    const float* Wk    = (const float*)d_in[2];
    const float* Wv    = (const float*)d_in[3];
    const float* Wo    = (const float*)d_in[4];
    const float* gamma = (const float*)d_in[5];
    float* out = (float*)d_out;

    char* wsb = (char*)d_ws;
    unsigned short* qh    = (unsigned short*)(wsb);                          // 1 MB
    unsigned short* kh    = (unsigned short*)(wsb + (1u << 20));             // 1 MB
    unsigned short* vh    = (unsigned short*)(wsb + (2u << 20));             // 8 MB
    unsigned short* What  = (unsigned short*)(wsb + (10u << 20));            // 160 KB
    unsigned short* WobF  = (unsigned short*)(wsb + (10u << 20) + (256u << 10)); // 128 KB
    unsigned short* Opart = (unsigned short*)(wsb + (11u << 20));            // 16.8 MB
    float*          ml    = (float*)         (wsb + (28u << 20));            // 256 KB

    wconv_kernel<<<320, 256, 0, stream>>>(Wq, Wk, Wv, Wo, What, WobF);

    dim3 g1(128, BATCH);
    qkv_kernel<<<g1, 256, 0, stream>>>(x, What, qh, kh, vh);

    dim3 g2(128, 2, BATCH);
    attn_kernel<<<g2, 256, 0, stream>>>(qh, kh, vh, Opart, ml);

    dim3 g3(128, BATCH);
    out_kernel<<<g3, 256, 0, stream>>>(Opart, ml, WobF, x, gamma, out);
}